// Round 1
// baseline (848.492 us; speedup 1.0000x reference)
//
#include <hip/hip_runtime.h>
#include <math.h>

constexpr int D_DIM = 2048;
constexpr int NEXP  = 64;
constexpr int TOPK  = 8;
constexpr int NTOK  = 16384;   // B*S = 4*4096
constexpr int TM    = 64;      // tokens per workgroup (lane = local token)
constexpr int BK    = 64;      // K chunk staged in LDS
constexpr int BLOCK = 512;     // 8 waves
constexpr int OPW   = 16;      // outputs per wave (per lane accumulators)
constexpr int HSTR  = 68;      // LDS h-tile row stride (floats), 16B-aligned, conflict-free
constexpr int OSTR  = 132;     // LDS out-tile row stride (128 outputs + pad)
constexpr int NSTR  = 68;      // LDS noise-tile row stride

__global__ __launch_bounds__(BLOCK, 1)
void noisy_topk_router(const float* __restrict__ hs,
                       const float* __restrict__ Wg,
                       const float* __restrict__ Wn,
                       const float* __restrict__ nz,
                       float* __restrict__ out)
{
    // 2 * 64 * 68 = 8704 floats (34.8 KB), reused as 64x132 logit tile in epilogue
    __shared__ float ldsH[2 * TM * HSTR];
    __shared__ float ldsN[TM * NSTR];   // 17.4 KB noise tile

    const int tid  = threadIdx.x;
    const int lane = tid & 63;                                   // local token
    const int w    = __builtin_amdgcn_readfirstlane(tid >> 6);   // wave id, SGPR
    const int t0   = blockIdx.x * TM;

    // wave w covers outputs [w*16, w*16+16): waves 0..3 -> gate rows, 4..7 -> noise rows
    const float* Wbase = (w < 4) ? (Wg + (size_t)(w * OPW) * D_DIM)
                                 : (Wn + (size_t)((w - 4) * OPW) * D_DIM);

    float acc[OPW];
#pragma unroll
    for (int o = 0; o < OPW; ++o) acc[o] = 0.0f;

    // staging mapping: 8 threads per token row, 128B contiguous per octet
    const int r = tid >> 3;   // token row 0..63
    const int c = tid & 7;    // float4 column 0..7
    const float* hrow = hs + (size_t)(t0 + r) * D_DIM;

    // prefetch + write chunk 0
    float4 pf[2];
#pragma unroll
    for (int p = 0; p < 2; ++p)
        pf[p] = *reinterpret_cast<const float4*>(hrow + (c + 8 * p) * 4);
#pragma unroll
    for (int p = 0; p < 2; ++p)
        *reinterpret_cast<float4*>(&ldsH[r * HSTR + (c + 8 * p) * 4]) = pf[p];

    constexpr int NCHUNK = D_DIM / BK;   // 32
    for (int ci = 0; ci < NCHUNK; ++ci) {
        __syncthreads();
        const float* ldsbuf = &ldsH[(ci & 1) * TM * HSTR];
        // prefetch next chunk into registers (overlaps with compute)
        if (ci + 1 < NCHUNK) {
#pragma unroll
            for (int p = 0; p < 2; ++p)
                pf[p] = *reinterpret_cast<const float4*>(hrow + (ci + 1) * BK + (c + 8 * p) * 4);
        }
        const int kb = ci * BK;
#pragma unroll 4
        for (int k4 = 0; k4 < BK / 4; ++k4) {
            float4 hv = *reinterpret_cast<const float4*>(&ldsbuf[lane * HSTR + k4 * 4]);
#pragma unroll
            for (int o = 0; o < OPW; ++o) {
                // wave-uniform address -> s_load_dwordx4, SGPR operand in v_fmac
                float4 wv = *reinterpret_cast<const float4*>(Wbase + (size_t)o * D_DIM + kb + k4 * 4);
                acc[o] = fmaf(wv.x, hv.x, acc[o]);
                acc[o] = fmaf(wv.y, hv.y, acc[o]);
                acc[o] = fmaf(wv.z, hv.z, acc[o]);
                acc[o] = fmaf(wv.w, hv.w, acc[o]);
            }
        }
        // write prefetched regs into the other buffer (safe: its readers passed top sync)
        if (ci + 1 < NCHUNK) {
            float* nbuf = &ldsH[((ci + 1) & 1) * TM * HSTR];
#pragma unroll
            for (int p = 0; p < 2; ++p)
                *reinterpret_cast<float4*>(&nbuf[r * HSTR + (c + 8 * p) * 4]) = pf[p];
        }
    }

    __syncthreads();   // all K-loop LDS reads done before reusing ldsH as logit tile

    // scatter accumulators into 64x132 logit tile: [tok][0..63]=gate, [tok][64..127]=noise
    {
        const int o0 = w * OPW;
#pragma unroll
        for (int q = 0; q < 4; ++q) {
            float4 v = make_float4(acc[q * 4 + 0], acc[q * 4 + 1], acc[q * 4 + 2], acc[q * 4 + 3]);
            *reinterpret_cast<float4*>(&ldsH[lane * OSTR + o0 + q * 4]) = v;
        }
    }
    // stage noise tile coalesced
    {
        const float* nrow = nz + (size_t)(t0 + r) * NEXP;
#pragma unroll
        for (int p = 0; p < 2; ++p) {
            float4 v = *reinterpret_cast<const float4*>(nrow + c * 4 + p * 32);
            *reinterpret_cast<float4*>(&ldsN[r * NSTR + c * 4 + p * 32]) = v;
        }
    }
    __syncthreads();

    if (tid < TM) {
        const int tok = t0 + tid;
        float l[NEXP];
        float mx = -3.0e38f;
#pragma unroll
        for (int e = 0; e < NEXP; ++e) {
            float g  = ldsH[tid * OSTR + e];
            float nl = ldsH[tid * OSTR + 64 + e];
            // numerically-stable softplus, matches jax.nn.softplus
            float sp = fmaxf(nl, 0.0f) + log1pf(expf(-fabsf(nl)));
            float le = fmaf(ldsN[tid * NSTR + e], sp, g);
            l[e] = le;
            mx = fmaxf(mx, le);
        }
        float sum = 0.0f;
#pragma unroll
        for (int e = 0; e < NEXP; ++e) { float p = expf(l[e] - mx); l[e] = p; sum += p; }
        float inv = 1.0f / sum;
#pragma unroll
        for (int e = 0; e < NEXP; ++e) l[e] *= inv;

        // save gates (before top-k clobbers l) for coalesced store
#pragma unroll
        for (int e = 0; e < NEXP; ++e) ldsH[tid * OSTR + e] = l[e];

        // stable top-8: strict '>' with ascending scan == jax tie-break (lowest index)
        float* vout = out + (size_t)tok * TOPK;
        float* iout = out + (size_t)NTOK * TOPK + (size_t)tok * TOPK;
#pragma unroll
        for (int p = 0; p < TOPK; ++p) {
            float m = -1.0f; int mi = 0;
#pragma unroll
            for (int e = 0; e < NEXP; ++e) {
                bool gt = l[e] > m;
                m  = gt ? l[e] : m;
                mi = gt ? e : mi;
            }
            vout[p] = m;
            iout[p] = (float)mi;   // harness reads d_out as float32
#pragma unroll
            for (int e = 0; e < NEXP; ++e) l[e] = (e == mi) ? -1.0f : l[e];
        }
    }
    __syncthreads();

    // coalesced gates store: [B,S,64] at offset 2*NTOK*TOPK
    {
        float* gout = out + (size_t)NTOK * TOPK * 2;
#pragma unroll
        for (int p = 0; p < 2; ++p) {
            float4 v = *reinterpret_cast<const float4*>(&ldsH[r * OSTR + c * 4 + p * 32]);
            *reinterpret_cast<float4*>(&gout[(size_t)(t0 + r) * NEXP + c * 4 + p * 32]) = v;
        }
    }
}

extern "C" void kernel_launch(void* const* d_in, const int* in_sizes, int n_in,
                              void* d_out, int out_size, void* d_ws, size_t ws_size,
                              hipStream_t stream) {
    const float* hs = (const float*)d_in[0];   // [4,4096,2048]
    const float* Wg = (const float*)d_in[1];   // [64,2048]
    const float* Wn = (const float*)d_in[2];   // [64,2048]
    const float* nz = (const float*)d_in[3];   // [4,4096,64]
    float* out = (float*)d_out;                // [vals | inds | gates]

    noisy_topk_router<<<NTOK / TM, BLOCK, 0, stream>>>(hs, Wg, Wn, nz, out);
}

// Round 3
// 264.447 us; speedup vs baseline: 3.2086x; 3.2086x over previous
//
#include <hip/hip_runtime.h>
#include <math.h>

typedef __attribute__((ext_vector_type(8))) _Float16 half8;
typedef __attribute__((ext_vector_type(4))) float    f32x4;

constexpr int D_DIM = 2048;
constexpr int NEXP  = 64;
constexpr int TOPK  = 8;
constexpr int NTOK  = 16384;        // B*S
constexpr int TM    = 64;           // tokens per WG
constexpr int BK    = 32;           // K per chunk (one 16x16x32 MFMA)
constexpr int NCH   = D_DIM / BK;   // 64 chunks
constexpr int OSTR  = 132;          // logit tile row stride (floats)
constexpr int NSTR  = 68;           // noise tile row stride (floats)
constexpr float WSCALE   = 4096.0f;     // W pre-scale (keeps fp16 lo out of subnormals)
constexpr float INV_WSC  = 1.0f / 4096.0f;

__device__ __forceinline__ unsigned short f16b(float x) {
    _Float16 h = (_Float16)x;                       // v_cvt_f16_f32 (RNE)
    return __builtin_bit_cast(unsigned short, h);
}
__device__ __forceinline__ float f16tof(unsigned short b) {
    return (float)__builtin_bit_cast(_Float16, b);
}

// ---------------------------------------------------------------------------
// K1: split W*4096 (gate rows 0..63, noise rows 64..127) into fp16 hi/lo,
// packed B-fragment-linear: ws ushort layout
//   [chunk c (stride 8192)][ntile T (stride 1024)]{ hi 512 | lo 512 }
//   lane l holds B[k = c*32 + (l>>4)*8 + j][n = T*16 + (l&15)]
// ---------------------------------------------------------------------------
__global__ void prep_w(const float* __restrict__ Wg, const float* __restrict__ Wn,
                       unsigned short* __restrict__ wsB)
{
    const int idx = blockIdx.x * blockDim.x + threadIdx.x;   // 0..32767
    const int n   = idx >> 8;      // output row 0..127
    const int K8  = idx & 255;     // k-octet
    const float* src = (n < 64) ? (Wg + (size_t)n * D_DIM)
                                : (Wn + (size_t)(n - 64) * D_DIM);
    float4 a = *reinterpret_cast<const float4*>(src + K8 * 8);
    float4 b = *reinterpret_cast<const float4*>(src + K8 * 8 + 4);

    float v[8] = {a.x, a.y, a.z, a.w, b.x, b.y, b.z, b.w};
    union { unsigned short u[8]; half8 s; } H, L;
#pragma unroll
    for (int j = 0; j < 8; ++j) {
        float xs = v[j] * WSCALE;
        unsigned short h = f16b(xs);
        H.u[j] = h;
        L.u[j] = f16b(xs - f16tof(h));
    }
    const int l = ((K8 & 3) * 16) + (n & 15);
    const size_t base = (size_t)(K8 >> 2) * 8192 + (size_t)(n >> 4) * 1024 + (size_t)l * 8;
    *reinterpret_cast<half8*>(wsB + base)       = H.s;
    *reinterpret_cast<half8*>(wsB + base + 512) = L.s;
}

// ---------------------------------------------------------------------------
// K2: GEMM (fp16x2 split, 3 MFMAs, parity-split hh accumulators)
//     + softplus/noise/softmax/top-8 epilogue
// ---------------------------------------------------------------------------
__global__ __launch_bounds__(512, 1)
void noisy_topk_router(const float* __restrict__ hs,
                       const unsigned short* __restrict__ wsB,
                       const float* __restrict__ nz,
                       float* __restrict__ out)
{
    // union LDS: K-loop stage = 2 buffers x (A_hi 4KB + A_lo 4KB) = 16384 B
    //            epilogue     = logits 64x132 f32 + noise 64x68 f32
    __shared__ __align__(16) char smem[33792 + 17408];
    unsigned short* stage  = reinterpret_cast<unsigned short*>(smem);
    float*          logits = reinterpret_cast<float*>(smem);
    float*          ldsN   = reinterpret_cast<float*>(smem + 33792);

    const int tid  = threadIdx.x;
    const int lane = tid & 63;
    const int w    = tid >> 6;                 // wave id = n-tile (outputs w*16..+16)
    const int t0   = blockIdx.x * TM;

    // staging role: thread owns one float4 (4 k) of one token row
    const int tok_s = tid >> 3;                // 0..63
    const int g2    = tid & 7;                 // k-quad 0..7
    const int mrow  = tok_s & 15;
    const int mtile = tok_s >> 4;
    const int g     = g2 >> 1;                 // k-octet 0..3
    const int half  = g2 & 1;
    const float* hrow = hs + (size_t)(t0 + tok_s) * D_DIM + g2 * 4;
    const int wr_hi = mtile * 512 + (g * 16 + mrow) * 8 + half * 4;   // ushort idx in buffer

    f32x4 accH0[4], accH1[4], accX[4];
#pragma unroll
    for (int mt = 0; mt < 4; ++mt) {
        accH0[mt] = (f32x4){0.f, 0.f, 0.f, 0.f};
        accH1[mt] = (f32x4){0.f, 0.f, 0.f, 0.f};
        accX[mt]  = (f32x4){0.f, 0.f, 0.f, 0.f};
    }

    auto cvt_write = [&](float4 v, unsigned short* buf) {
        float p[4] = {v.x, v.y, v.z, v.w};
        unsigned int Hp[2], Lp[2];
#pragma unroll
        for (int q = 0; q < 2; ++q) {
            unsigned short h0 = f16b(p[2*q]);
            unsigned short h1 = f16b(p[2*q+1]);
            unsigned short l0 = f16b(p[2*q]   - f16tof(h0));
            unsigned short l1 = f16b(p[2*q+1] - f16tof(h1));
            Hp[q] = (unsigned int)h0 | ((unsigned int)h1 << 16);
            Lp[q] = (unsigned int)l0 | ((unsigned int)l1 << 16);
        }
        *reinterpret_cast<uint2*>(buf + wr_hi)        = make_uint2(Hp[0], Hp[1]);
        *reinterpret_cast<uint2*>(buf + 2048 + wr_hi) = make_uint2(Lp[0], Lp[1]);
    };

    // stage chunk 0; prefetch chunk 1 (distance-2 pipeline)
    cvt_write(*reinterpret_cast<const float4*>(hrow), stage);
    float4 pf_cur = *reinterpret_cast<const float4*>(hrow + BK);
    __syncthreads();

    const unsigned short* bp0 = wsB + (size_t)w * 1024 + (size_t)lane * 8;

    auto kstep = [&](int c, f32x4* accH) {
        const int buf = c & 1;
        float4 pf_next;
        if (c + 2 < NCH)
            pf_next = *reinterpret_cast<const float4*>(hrow + (c + 2) * BK);

        // B fragments from L2 (fragment-linear pack)
        const unsigned short* bp = bp0 + (size_t)c * 8192;
        half8 bhi = *reinterpret_cast<const half8*>(bp);
        half8 blo = *reinterpret_cast<const half8*>(bp + 512);

        // A fragments from LDS
        const unsigned short* sb = stage + buf * 4096;
        half8 ahi[4], alo[4];
#pragma unroll
        for (int mt = 0; mt < 4; ++mt) {
            ahi[mt] = *reinterpret_cast<const half8*>(sb + mt * 512 + lane * 8);
            alo[mt] = *reinterpret_cast<const half8*>(sb + 2048 + mt * 512 + lane * 8);
        }

#pragma unroll
        for (int mt = 0; mt < 4; ++mt) {
            accH[mt] = __builtin_amdgcn_mfma_f32_16x16x32_f16(ahi[mt], bhi, accH[mt], 0, 0, 0);
            accX[mt] = __builtin_amdgcn_mfma_f32_16x16x32_f16(ahi[mt], blo, accX[mt], 0, 0, 0);
            accX[mt] = __builtin_amdgcn_mfma_f32_16x16x32_f16(alo[mt], bhi, accX[mt], 0, 0, 0);
        }

        if (c + 1 < NCH) {
            cvt_write(pf_cur, stage + (buf ^ 1) * 4096);
            pf_cur = pf_next;
        }
        __syncthreads();
    };

    for (int c2 = 0; c2 < NCH; c2 += 2) {
        kstep(c2,     accH0);   // even chunks -> accH0
        kstep(c2 + 1, accH1);   // odd chunks  -> accH1
    }

    // scatter accumulators to logit tile: D[row=(lane>>4)*4+reg][col=lane&15]
    {
        const int colb = w * 16 + (lane & 15);
        const int rowb = (lane >> 4) * 4;
#pragma unroll
        for (int mt = 0; mt < 4; ++mt) {
            f32x4 s = accH0[mt] + accH1[mt] + accX[mt];
#pragma unroll
            for (int r = 0; r < 4; ++r)
                logits[(mt * 16 + rowb + r) * OSTR + colb] = s[r] * INV_WSC;
        }
    }
    // stage noise tile coalesced
    {
        const int rr = tid >> 3;
        const int cc = tid & 7;
        const float* nrow = nz + (size_t)(t0 + rr) * NEXP;
#pragma unroll
        for (int p = 0; p < 2; ++p) {
            float4 v = *reinterpret_cast<const float4*>(nrow + cc * 4 + p * 32);
            *reinterpret_cast<float4*>(&ldsN[rr * NSTR + cc * 4 + p * 32]) = v;
        }
    }
    __syncthreads();

    if (tid < TM) {
        const int tok = t0 + tid;
        float l[NEXP];
        float mx = -3.0e38f;
#pragma unroll
        for (int e = 0; e < NEXP; ++e) {
            float gsc = logits[tid * OSTR + e];
            float nl  = logits[tid * OSTR + 64 + e];
            float sp  = fmaxf(nl, 0.0f) + log1pf(expf(-fabsf(nl)));   // softplus
            float le  = fmaf(ldsN[tid * NSTR + e], sp, gsc);
            l[e] = le;
            mx = fmaxf(mx, le);
        }
        float sum = 0.0f;
#pragma unroll
        for (int e = 0; e < NEXP; ++e) { float p = expf(l[e] - mx); l[e] = p; sum += p; }
        float inv = 1.0f / sum;
#pragma unroll
        for (int e = 0; e < NEXP; ++e) l[e] *= inv;

        // save gates for coalesced store
#pragma unroll
        for (int e = 0; e < NEXP; ++e) logits[tid * OSTR + e] = l[e];

        float* vout = out + (size_t)tok * TOPK;
        float* iout = out + (size_t)NTOK * TOPK + (size_t)tok * TOPK;
#pragma unroll
        for (int p = 0; p < TOPK; ++p) {
            float m = -1.0f; int mi = 0;
#pragma unroll
            for (int e = 0; e < NEXP; ++e) {
                bool gt = l[e] > m;        // strict > + ascending scan = lowest-index tie-break
                m  = gt ? l[e] : m;
                mi = gt ? e : mi;
            }
            vout[p] = m;
            iout[p] = (float)mi;
#pragma unroll
            for (int e = 0; e < NEXP; ++e) l[e] = (e == mi) ? -1.0f : l[e];
        }
    }
    __syncthreads();

    // coalesced gates store
    {
        const int rr = tid >> 3;
        const int cc = tid & 7;
        float* gout = out + (size_t)NTOK * TOPK * 2;
#pragma unroll
        for (int p = 0; p < 2; ++p) {
            float4 v = *reinterpret_cast<const float4*>(&logits[rr * OSTR + cc * 4 + p * 32]);
            *reinterpret_cast<float4*>(&gout[(size_t)(t0 + rr) * NEXP + cc * 4 + p * 32]) = v;
        }
    }
}

extern "C" void kernel_launch(void* const* d_in, const int* in_sizes, int n_in,
                              void* d_out, int out_size, void* d_ws, size_t ws_size,
                              hipStream_t stream) {
    const float* hs = (const float*)d_in[0];   // [4,4096,2048]
    const float* Wg = (const float*)d_in[1];   // [64,2048]
    const float* Wn = (const float*)d_in[2];   // [64,2048]
    const float* nz = (const float*)d_in[3];   // [4,4096,64]
    float* out = (float*)d_out;
    unsigned short* wsB = (unsigned short*)d_ws;   // 1 MB B-fragment pack (fp16 bits)

    prep_w<<<64, 512, 0, stream>>>(Wg, Wn, wsB);
    noisy_topk_router<<<NTOK / TM, 512, 0, stream>>>(hs, wsB, nz, out);
}